// Round 2
// baseline (597.008 us; speedup 1.0000x reference)
//
#include <hip/hip_runtime.h>
#include <cstdint>
#include <cstddef>

typedef unsigned short u16;
typedef __attribute__((ext_vector_type(8))) short bf16x8;   // 8 bf16 = 4 VGPRs
typedef __attribute__((ext_vector_type(4))) float f32x4;    // MFMA 16x16 accum

#define NB    64    // batch
#define NTOK  625   // tokens (25x25)
#define NTOKP 640   // padded tokens
#define DDIM  512
#define NH    8
#define DH    64

__device__ __forceinline__ float bf2f(u16 v) {
    return __uint_as_float(((unsigned int)v) << 16);
}
__device__ __forceinline__ u16 f2bf(float f) {
    unsigned int x = __float_as_uint(f);
    unsigned int r = (x + 0x7fffu + ((x >> 16) & 1u)) >> 16;  // RNE
    return (u16)r;
}

// ---------------- transpose x: f32 (b, d, n) -> bf16 tokens (b, n, d) ----------------
__global__ __launch_bounds__(256) void k_transpose_x(const float* __restrict__ x,
                                                     u16* __restrict__ tokens) {
    __shared__ u16 T[64][66];
    int b = blockIdx.z, ct = blockIdx.y, it = blockIdx.x;
    int t = threadIdx.x;
    int i0 = it * 64, c0 = ct * 64;
#pragma unroll
    for (int r = 0; r < 2; r++) {
        int c = (t >> 3) + r * 32;
        int i8 = (t & 7) * 8;
        const float* s = x + ((size_t)b * DDIM + c0 + c) * NTOK + i0 + i8;
#pragma unroll
        for (int u = 0; u < 8; u++)
            T[c][i8 + u] = (i0 + i8 + u < NTOK) ? f2bf(s[u]) : (u16)0;
    }
    __syncthreads();
#pragma unroll
    for (int r = 0; r < 2; r++) {
        int i = (t >> 3) + r * 32;
        int c8 = (t & 7) * 8;
        int gi = i0 + i;
        if (gi < NTOK) {
            u16* d = tokens + ((size_t)b * NTOK + gi) * DDIM + c0 + c8;
#pragma unroll
            for (int u = 0; u < 8; u++) d[u] = T[c8 + u][i];
        }
    }
}

// ---------------- weight transpose: f32 src[R][C] -> bf16 dst[C][R] (R,C mult of 64)
__global__ __launch_bounds__(256) void k_transpose_w(const float* __restrict__ src,
                                                     u16* __restrict__ dst, int R, int C) {
    __shared__ u16 T[64][66];
    int r0 = blockIdx.y * 64, c0 = blockIdx.x * 64;
    int t = threadIdx.x;
#pragma unroll
    for (int rr = 0; rr < 2; rr++) {
        int r = (t >> 3) + rr * 32;
        int c8 = (t & 7) * 8;
        const float* s = src + (size_t)(r0 + r) * C + c0 + c8;
#pragma unroll
        for (int u = 0; u < 8; u++) T[r][c8 + u] = f2bf(s[u]);
    }
    __syncthreads();
#pragma unroll
    for (int rr = 0; rr < 2; rr++) {
        int c = (t >> 3) + rr * 32;
        int r8 = (t & 7) * 8;
        u16* d = dst + (size_t)(c0 + c) * R + r0 + r8;
#pragma unroll
        for (int u = 0; u < 8; u++) d[u] = T[r8 + u][c];
    }
}

// ---------------- bias expand: bias_full[m][i][j] = rpb[rpi[i,j]][m] (f32) ----------------
__global__ __launch_bounds__(256) void k_bias(const int* __restrict__ rpi,
                                              const float* __restrict__ rpb,
                                              float* __restrict__ bias_full) {
    int e = blockIdx.x * 256 + threadIdx.x;
    if (e >= NTOK * NTOK) return;
    int id = rpi[e];
#pragma unroll
    for (int m = 0; m < NH; m++)
        bias_full[(size_t)m * NTOK * NTOK + e] = rpb[id * NH + m];
}

// ---------------- QKV GEMM: qkv[b,i,j] = sum_c tokens[b,i,c] * wT[j,c] ----------------
// q (j<512, scaled 0.125) and k (512..1023) -> qk[b][i][1024]; v -> vT[b][m][t][640]
__global__ __launch_bounds__(256) void k_qkv(const u16* __restrict__ tokens,
                                             const u16* __restrict__ wT,
                                             u16* __restrict__ qk, u16* __restrict__ vT) {
    __shared__ u16 As[128][40];
    __shared__ u16 Bs[128][40];
    int b = blockIdx.z, jt = blockIdx.y, it = blockIdx.x;
    int i0 = it * 128, j0 = jt * 128;
    int t = threadIdx.x;
    int w = t >> 6, lane = t & 63, quad = lane >> 4, l15 = lane & 15;
    int wr = w >> 1, wc = w & 1;
    f32x4 acc[4][4] = {};
    int srow = t >> 1, sc = (t & 1) * 16;
    const u16* aptr = tokens + ((size_t)b * NTOK + (i0 + srow)) * DDIM + sc;
    const u16* bptr = wT + (size_t)(j0 + srow) * DDIM + sc;
    bool arow_ok = (i0 + srow) < NTOK;
    for (int k0 = 0; k0 < DDIM; k0 += 32) {
        uint4 av0, av1;
        if (arow_ok) { av0 = *(const uint4*)aptr; av1 = *(const uint4*)(aptr + 8); }
        else { av0 = make_uint4(0, 0, 0, 0); av1 = av0; }
        uint4 bv0 = *(const uint4*)bptr, bv1 = *(const uint4*)(bptr + 8);
        aptr += 32; bptr += 32;
        __syncthreads();
        *(uint4*)&As[srow][sc] = av0; *(uint4*)&As[srow][sc + 8] = av1;
        *(uint4*)&Bs[srow][sc] = bv0; *(uint4*)&Bs[srow][sc + 8] = bv1;
        __syncthreads();
        bf16x8 af[4], bfv[4];
#pragma unroll
        for (int q2 = 0; q2 < 4; q2++) {
            af[q2]  = *(const bf16x8*)&As[wr * 64 + q2 * 16 + l15][quad * 8];
            bfv[q2] = *(const bf16x8*)&Bs[wc * 64 + q2 * 16 + l15][quad * 8];
        }
#pragma unroll
        for (int ii = 0; ii < 4; ii++)
#pragma unroll
            for (int jj = 0; jj < 4; jj++)
                acc[ii][jj] = __builtin_amdgcn_mfma_f32_16x16x32_bf16(af[ii], bfv[jj], acc[ii][jj], 0, 0, 0);
    }
    // epilogue: D rows = i (quad*4+reg), cols = j (l15)
    if (j0 < 1024) {
        float scale = (j0 < 512) ? 0.125f : 1.0f;
#pragma unroll
        for (int ii = 0; ii < 4; ii++) {
            int gib = i0 + wr * 64 + ii * 16 + quad * 4;
#pragma unroll
            for (int jj = 0; jj < 4; jj++) {
                int gj = j0 + wc * 64 + jj * 16 + l15;
#pragma unroll
                for (int r = 0; r < 4; r++) {
                    if (gib + r < NTOK)
                        qk[((size_t)b * NTOK + gib + r) * 1024 + gj] = f2bf(acc[ii][jj][r] * scale);
                }
            }
        }
    } else {
#pragma unroll
        for (int ii = 0; ii < 4; ii++) {
            int gib = i0 + wr * 64 + ii * 16 + quad * 4;
#pragma unroll
            for (int jj = 0; jj < 4; jj++) {
                int gj = j0 + wc * 64 + jj * 16 + l15 - 1024;
                int hd = gj >> 6, tc = gj & 63;
#pragma unroll
                for (int r = 0; r < 4; r++) {
                    int gi = gib + r;
                    u16 val = (gi < NTOK) ? f2bf(acc[ii][jj][r]) : (u16)0;
                    vT[(((size_t)b * NH + hd) * DH + tc) * NTOKP + gi] = val;  // gi<640 always
                }
            }
        }
    }
}

// ---------------- flash attention: per (b, m, 64-row q tile) ----------------
__global__ __launch_bounds__(256) void k_attn(const u16* __restrict__ qk,
                                              const u16* __restrict__ vT,
                                              const float* __restrict__ bias_full,
                                              u16* __restrict__ attnout) {
    __shared__ u16 Qs[64][72];
    __shared__ u16 Ks[64][72];
    __shared__ u16 Vs[64][72];
    __shared__ u16 Ps[64][72];
    int b = blockIdx.z, m = blockIdx.y, it = blockIdx.x;
    int i0 = it * 64;
    int t = threadIdx.x;
    int w = t >> 6, lane = t & 63, quad = lane >> 4, l15 = lane & 15;
#pragma unroll
    for (int r = 0; r < 2; r++) {  // load Q tile
        int row = (t >> 3) + r * 32;
        int t8 = (t & 7) * 8;
        int gi = i0 + row;
        uint4 v;
        if (gi < NTOK) v = *(const uint4*)(qk + ((size_t)b * NTOK + gi) * 1024 + m * DH + t8);
        else v = make_uint4(0, 0, 0, 0);
        *(uint4*)&Qs[row][t8] = v;
    }
    float mprev[4], lsum[4];
#pragma unroll
    for (int r = 0; r < 4; r++) { mprev[r] = -INFINITY; lsum[r] = 0.f; }
    f32x4 oacc[4] = {};
    const float* bias_m = bias_full + (size_t)m * NTOK * NTOK;
    const u16* vbase = vT + ((size_t)b * NH + m) * DH * NTOKP;

    for (int jt = 0; jt < 10; jt++) {
        int j0 = jt * 64;
        __syncthreads();  // prior iteration's Ks/Vs reads done
#pragma unroll
        for (int r = 0; r < 2; r++) {  // stage K (rows=j, cols=t) and V (rows=t, cols=j)
            int row = (t >> 3) + r * 32;
            int c8 = (t & 7) * 8;
            int gj = j0 + row;
            uint4 kv;
            if (gj < NTOK) kv = *(const uint4*)(qk + ((size_t)b * NTOK + gj) * 1024 + 512 + m * DH + c8);
            else kv = make_uint4(0, 0, 0, 0);
            *(uint4*)&Ks[row][c8] = kv;
            uint4 vv = *(const uint4*)(vbase + (size_t)row * NTOKP + j0 + c8);
            *(uint4*)&Vs[row][c8] = vv;
        }
        __syncthreads();
        // S accum init = bias (masks OOB j with -1e30)
        f32x4 s[4];
#pragma unroll
        for (int jj = 0; jj < 4; jj++) {
            int gj = j0 + jj * 16 + l15;
#pragma unroll
            for (int r = 0; r < 4; r++) {
                int gi = i0 + w * 16 + quad * 4 + r;
                float bv;
                if (gj >= NTOK) bv = -1e30f;
                else if (gi >= NTOK) bv = 0.f;
                else bv = bias_m[(size_t)gi * NTOK + gj];
                s[jj][r] = bv;
            }
        }
        bf16x8 aq[2];
#pragma unroll
        for (int kk = 0; kk < 2; kk++)
            aq[kk] = *(const bf16x8*)&Qs[w * 16 + l15][kk * 32 + quad * 8];
#pragma unroll
        for (int jj = 0; jj < 4; jj++)
#pragma unroll
            for (int kk = 0; kk < 2; kk++) {
                bf16x8 bk = *(const bf16x8*)&Ks[jj * 16 + l15][kk * 32 + quad * 8];
                s[jj] = __builtin_amdgcn_mfma_f32_16x16x32_bf16(aq[kk], bk, s[jj], 0, 0, 0);
            }
        // online softmax (rows live on 16-lane groups; reduce via shfl_xor 1..8)
        float mnew[4], alpha[4];
#pragma unroll
        for (int r = 0; r < 4; r++) {
            float mx = fmaxf(fmaxf(s[0][r], s[1][r]), fmaxf(s[2][r], s[3][r]));
#pragma unroll
            for (int d = 1; d < 16; d <<= 1) mx = fmaxf(mx, __shfl_xor(mx, d, 64));
            mnew[r] = fmaxf(mprev[r], mx);
            alpha[r] = __expf(mprev[r] - mnew[r]);
        }
        float ps[4][4];
        float rs[4];
#pragma unroll
        for (int r = 0; r < 4; r++) {
            float sum = 0.f;
#pragma unroll
            for (int jj = 0; jj < 4; jj++) {
                float p = __expf(s[jj][r] - mnew[r]);
                ps[jj][r] = p;
                sum += p;
            }
            rs[r] = sum;
        }
#pragma unroll
        for (int r = 0; r < 4; r++) {
            float sum = rs[r];
#pragma unroll
            for (int d = 1; d < 16; d <<= 1) sum += __shfl_xor(sum, d, 64);
            lsum[r] = lsum[r] * alpha[r] + sum;
            mprev[r] = mnew[r];
        }
#pragma unroll
        for (int tt = 0; tt < 4; tt++)
#pragma unroll
            for (int r = 0; r < 4; r++) oacc[tt][r] *= alpha[r];
        // P: C-layout -> LDS (per-wave rows), re-read in A-layout
#pragma unroll
        for (int jj = 0; jj < 4; jj++)
#pragma unroll
            for (int r = 0; r < 4; r++)
                Ps[w * 16 + quad * 4 + r][jj * 16 + l15] = f2bf(ps[jj][r]);
        __syncthreads();
        bf16x8 ap[2];
#pragma unroll
        for (int kk = 0; kk < 2; kk++)
            ap[kk] = *(const bf16x8*)&Ps[w * 16 + l15][kk * 32 + quad * 8];
#pragma unroll
        for (int tt = 0; tt < 4; tt++)
#pragma unroll
            for (int kk = 0; kk < 2; kk++) {
                bf16x8 bv = *(const bf16x8*)&Vs[tt * 16 + l15][kk * 32 + quad * 8];
                oacc[tt] = __builtin_amdgcn_mfma_f32_16x16x32_bf16(ap[kk], bv, oacc[tt], 0, 0, 0);
            }
    }
#pragma unroll
    for (int tt = 0; tt < 4; tt++)
#pragma unroll
        for (int r = 0; r < 4; r++) {
            int gi = i0 + w * 16 + quad * 4 + r;
            if (gi < NTOK)
                attnout[((size_t)b * NTOK + gi) * DDIM + m * DH + tt * 16 + l15] =
                    f2bf(oacc[tt][r] / lsum[r]);
        }
}

// ---------------- out GEMM (computes C^T): out[b,ch,i] = sum_c attnout[b,i,c]*woT[ch,c]
__global__ __launch_bounds__(256) void k_out(const u16* __restrict__ attnout,
                                             const u16* __restrict__ woT,
                                             float* __restrict__ out) {
    __shared__ u16 As[128][40];
    __shared__ u16 Bs[128][40];
    int b = blockIdx.z, jt = blockIdx.y, it = blockIdx.x;
    int j0 = jt * 128, i0 = it * 128;   // j = output channel (M), i = token (N)
    int t = threadIdx.x;
    int w = t >> 6, lane = t & 63, quad = lane >> 4, l15 = lane & 15;
    int wr = w >> 1, wc = w & 1;
    f32x4 acc[4][4] = {};
    int srow = t >> 1, sc = (t & 1) * 16;
    const u16* aptr = woT + (size_t)(j0 + srow) * DDIM + sc;
    const u16* bptr = attnout + ((size_t)b * NTOK + i0 + srow) * DDIM + sc;
    bool brow_ok = (i0 + srow) < NTOK;
    for (int k0 = 0; k0 < DDIM; k0 += 32) {
        uint4 av0 = *(const uint4*)aptr, av1 = *(const uint4*)(aptr + 8);
        uint4 bv0, bv1;
        if (brow_ok) { bv0 = *(const uint4*)bptr; bv1 = *(const uint4*)(bptr + 8); }
        else { bv0 = make_uint4(0, 0, 0, 0); bv1 = bv0; }
        aptr += 32; bptr += 32;
        __syncthreads();
        *(uint4*)&As[srow][sc] = av0; *(uint4*)&As[srow][sc + 8] = av1;
        *(uint4*)&Bs[srow][sc] = bv0; *(uint4*)&Bs[srow][sc + 8] = bv1;
        __syncthreads();
        bf16x8 af[4], bfv[4];
#pragma unroll
        for (int q2 = 0; q2 < 4; q2++) {
            af[q2]  = *(const bf16x8*)&As[wr * 64 + q2 * 16 + l15][quad * 8];
            bfv[q2] = *(const bf16x8*)&Bs[wc * 64 + q2 * 16 + l15][quad * 8];
        }
#pragma unroll
        for (int ii = 0; ii < 4; ii++)
#pragma unroll
            for (int jj = 0; jj < 4; jj++)
                acc[ii][jj] = __builtin_amdgcn_mfma_f32_16x16x32_bf16(af[ii], bfv[jj], acc[ii][jj], 0, 0, 0);
    }
    // D rows = channel, cols = token -> coalesced (b, d, n) f32 store
#pragma unroll
    for (int ii = 0; ii < 4; ii++)
#pragma unroll
        for (int jj = 0; jj < 4; jj++) {
            int gi = i0 + wc * 64 + jj * 16 + l15;
            if (gi >= NTOK) continue;
#pragma unroll
            for (int r = 0; r < 4; r++) {
                int gj = j0 + wr * 64 + ii * 16 + quad * 4 + r;
                out[((size_t)b * DDIM + gj) * NTOK + gi] = acc[ii][jj][r];
            }
        }
}

extern "C" void kernel_launch(void* const* d_in, const int* in_sizes, int n_in,
                              void* d_out, int out_size, void* d_ws, size_t ws_size,
                              hipStream_t stream) {
    const float* x    = (const float*)d_in[0];   // (64,512,25,25) f32
    const float* wqkv = (const float*)d_in[1];   // (512,1536) f32
    const float* wout = (const float*)d_in[2];   // (512,512) f32
    const float* rpb  = (const float*)d_in[3];   // (2401,8) f32
    const int*   rpi  = (const int*)d_in[4];     // (625,625) int32
    float* out = (float*)d_out;

    char* ws = (char*)d_ws;
    size_t off = 0;
    auto alloc = [&](size_t nbytes) -> void* {
        void* p = ws + off;
        off += (nbytes + 255) & ~(size_t)255;
        return p;
    };
    u16* tokens   = (u16*)alloc((size_t)NB * NTOK * DDIM * 2);     // 41 MB (reused as attnout)
    u16* qk       = (u16*)alloc((size_t)NB * NTOK * 1024 * 2);     // 82 MB
    u16* vT       = (u16*)alloc((size_t)NB * NH * DH * NTOKP * 2); // 42 MB
    u16* wqkvT    = (u16*)alloc((size_t)1536 * DDIM * 2);
    u16* woutT    = (u16*)alloc((size_t)DDIM * DDIM * 2);
    float* biasf  = (float*)alloc((size_t)NH * NTOK * NTOK * 4);   // 12.5 MB
    u16* attnout  = tokens;  // tokens is dead after k_qkv

    k_transpose_x<<<dim3(10, 8, NB), 256, 0, stream>>>(x, tokens);
    k_transpose_w<<<dim3(1536 / 64, DDIM / 64), 256, 0, stream>>>(wqkv, wqkvT, DDIM, 1536);
    k_transpose_w<<<dim3(DDIM / 64, DDIM / 64), 256, 0, stream>>>(wout, woutT, DDIM, DDIM);
    k_bias<<<dim3((NTOK * NTOK + 255) / 256), 256, 0, stream>>>(rpi, rpb, biasf);
    k_qkv<<<dim3(5, 12, NB), 256, 0, stream>>>(tokens, wqkvT, qk, vT);
    k_attn<<<dim3(10, NH, NB), 256, 0, stream>>>(qk, vT, biasf, attnout);
    k_out<<<dim3(5, 4, NB), 256, 0, stream>>>(attnout, woutT, out);
}

// Round 3
// 487.823 us; speedup vs baseline: 1.2238x; 1.2238x over previous
//
#include <hip/hip_runtime.h>
#include <cstdint>
#include <cstddef>

typedef unsigned short u16;
typedef __attribute__((ext_vector_type(8))) short bf16x8;   // 8 bf16 = 4 VGPRs
typedef __attribute__((ext_vector_type(4))) float f32x4;    // MFMA 16x16 accum

#define NB    64    // batch
#define NTOK  625   // tokens (25x25)
#define NTOKP 640   // padded tokens
#define DDIM  512
#define NH    8
#define DH    64

__device__ __forceinline__ float bf2f(u16 v) {
    return __uint_as_float(((unsigned int)v) << 16);
}
__device__ __forceinline__ u16 f2bf(float f) {           // RNE
    unsigned int x = __float_as_uint(f);
    unsigned int r = (x + 0x7fffu + ((x >> 16) & 1u)) >> 16;
    return (u16)r;
}
__device__ __forceinline__ u16 f2bf_fast(float f) {      // round-half-up (2 ops)
    return (u16)((__float_as_uint(f) + 0x8000u) >> 16);
}

// async global->LDS, 16B per lane (m97 pattern); fallback = sync staging
#if __has_builtin(__builtin_amdgcn_global_load_lds)
#define HAVE_GLDS 1
typedef const __attribute__((address_space(1))) void gas_void;
typedef __attribute__((address_space(3))) void las_void;
__device__ __forceinline__ void glds16(const void* g, void* l) {
    __builtin_amdgcn_global_load_lds((gas_void*)g, (las_void*)l, 16, 0, 0);
}
#else
#define HAVE_GLDS 0
__device__ __forceinline__ void glds16(const void* g, void* l) {
    *(uint4*)l = *(const uint4*)g;
}
#endif

// ---------------- transpose x: f32 (b, d, n) -> bf16 tokens (b, n, d) ----------------
__global__ __launch_bounds__(256) void k_transpose_x(const float* __restrict__ x,
                                                     u16* __restrict__ tokens) {
    __shared__ u16 T[64][66];
    int b = blockIdx.z, ct = blockIdx.y, it = blockIdx.x;
    int t = threadIdx.x;
    int i0 = it * 64, c0 = ct * 64;
#pragma unroll
    for (int r = 0; r < 2; r++) {
        int c = (t >> 3) + r * 32;
        int i8 = (t & 7) * 8;
        const float* s = x + ((size_t)b * DDIM + c0 + c) * NTOK + i0 + i8;
#pragma unroll
        for (int u = 0; u < 8; u++)
            T[c][i8 + u] = (i0 + i8 + u < NTOK) ? f2bf(s[u]) : (u16)0;
    }
    __syncthreads();
#pragma unroll
    for (int r = 0; r < 2; r++) {
        int i = (t >> 3) + r * 32;
        int c8 = (t & 7) * 8;
        int gi = i0 + i;
        if (gi < NTOK) {
            u16* d = tokens + ((size_t)b * NTOK + gi) * DDIM + c0 + c8;
#pragma unroll
            for (int u = 0; u < 8; u++) d[u] = T[c8 + u][i];
        }
    }
}

// ---------------- weight transpose: f32 src[R][C] -> bf16 dst[C][R] ----------------
__global__ __launch_bounds__(256) void k_transpose_w(const float* __restrict__ src,
                                                     u16* __restrict__ dst, int R, int C) {
    __shared__ u16 T[64][66];
    int r0 = blockIdx.y * 64, c0 = blockIdx.x * 64;
    int t = threadIdx.x;
#pragma unroll
    for (int rr = 0; rr < 2; rr++) {
        int r = (t >> 3) + rr * 32;
        int c8 = (t & 7) * 8;
        const float* s = src + (size_t)(r0 + r) * C + c0 + c8;
#pragma unroll
        for (int u = 0; u < 8; u++) T[r][c8 + u] = f2bf(s[u]);
    }
    __syncthreads();
#pragma unroll
    for (int rr = 0; rr < 2; rr++) {
        int c = (t >> 3) + rr * 32;
        int r8 = (t & 7) * 8;
        u16* d = dst + (size_t)(c0 + c) * R + r0 + r8;
#pragma unroll
        for (int u = 0; u < 8; u++) d[u] = T[r8 + u][c];
    }
}

// ---------------- bias expand into MFMA C-layout (bf16), masking folded in ----------
// biasC[((m*10+jt)*10+it)*4096 + t*16 + jj*4 + r]; thread t of the attn block.
__global__ __launch_bounds__(256) void k_bias(const int* __restrict__ rpi,
                                              const float* __restrict__ rpb,
                                              u16* __restrict__ biasC) {
    int blk = blockIdx.x;               // 800 = m*100 + jt*10 + it
    int m = blk / 100, jt = (blk / 10) % 10, it = blk % 10;
    int t = threadIdx.x;
    u16 vals[16];
#pragma unroll
    for (int jj = 0; jj < 4; jj++) {
        int gj = jt * 64 + jj * 16 + (t & 15);
#pragma unroll
        for (int r = 0; r < 4; r++) {
            int gi = it * 64 + (t >> 6) * 16 + ((t >> 4) & 3) * 4 + r;
            float v;
            if (gj >= NTOK) v = -1e30f;
            else if (gi >= NTOK) v = 0.f;
            else v = rpb[rpi[gi * NTOK + gj] * NH + m];
            vals[jj * 4 + r] = f2bf(v);
        }
    }
    u16* d = biasC + ((size_t)(m * 10 + jt) * 10 + it) * 4096 + t * 16;
    *(uint4*)d = *(uint4*)&vals[0];
    *(uint4*)(d + 8) = *(uint4*)&vals[8];
}

// ---------------- QKV GEMM (global_load_lds staging + coalesced LDS epilogues) ------
// q (scaled 0.125) -> qk[b][i][0..511]; k -> qk[b][i][512..1023];
// v -> vT[b][hd][tc][n'] with n' = tile*64 + pi(tok), pi(v) = (v&15)*4 + (v>>4).
__global__ __launch_bounds__(256) void k_qkv(const u16* __restrict__ tokens,
                                             const u16* __restrict__ wT,
                                             u16* __restrict__ qk, u16* __restrict__ vT) {
    __shared__ u16 SMEM[9216];          // As [128][32] | Bs [128][32]; reused as T/T2
    int b = blockIdx.z, jt = blockIdx.y, it = blockIdx.x;
    int i0 = it * 128, j0 = jt * 128;
    int t = threadIdx.x;
    int w = t >> 6, lane = t & 63, quad = lane >> 4, l15 = lane & 15;
    int wr = w >> 1, wc = w & 1;
    f32x4 acc[4][4] = {};
    const u16* abase = tokens + ((size_t)b * NTOK + i0) * DDIM;
    const u16* bbase = wT + (size_t)j0 * DDIM;
    for (int k0 = 0; k0 < DDIM; k0 += 32) {
        __syncthreads();
#pragma unroll
        for (int c = 0; c < 2; c++) {
            int unit = c * 256 + t;
            int row = unit >> 2, col = (unit & 3) * 8;
            glds16(abase + (size_t)row * DDIM + k0 + col, SMEM + unit * 8);
            glds16(bbase + (size_t)row * DDIM + k0 + col, SMEM + 4096 + unit * 8);
        }
        __syncthreads();
        bf16x8 af[4], bfv[4];
#pragma unroll
        for (int q2 = 0; q2 < 4; q2++) {
            af[q2]  = *(const bf16x8*)&SMEM[(wr * 64 + q2 * 16 + l15) * 32 + quad * 8];
            bfv[q2] = *(const bf16x8*)&SMEM[4096 + (wc * 64 + q2 * 16 + l15) * 32 + quad * 8];
        }
#pragma unroll
        for (int ii = 0; ii < 4; ii++)
#pragma unroll
            for (int jj = 0; jj < 4; jj++)
                acc[ii][jj] = __builtin_amdgcn_mfma_f32_16x16x32_bf16(af[ii], bfv[jj], acc[ii][jj], 0, 0, 0);
    }
    __syncthreads();                    // SMEM reuse
    if (jt < 8) {
        // q/k epilogue via T2[64][136]: rows=token half, cols=128 channels
        float scale = (j0 < 512) ? 0.125f : 1.0f;
#pragma unroll
        for (int h = 0; h < 2; h++) {
            if (h) __syncthreads();
            if (wr == h) {
#pragma unroll
                for (int ii = 0; ii < 4; ii++)
#pragma unroll
                    for (int jj = 0; jj < 4; jj++)
#pragma unroll
                        for (int r = 0; r < 4; r++)
                            SMEM[(ii * 16 + quad * 4 + r) * 136 + wc * 64 + jj * 16 + l15] =
                                f2bf(acc[ii][jj][r] * scale);
            }
            __syncthreads();
#pragma unroll
            for (int g = 0; g < 4; g++) {
                int unit = g * 256 + t;
                int tok = unit >> 4, ch8 = (unit & 15) * 8;
                int gi = i0 + h * 64 + tok;
                if (gi < NTOK)
                    *(uint4*)(qk + ((size_t)b * NTOK + gi) * 1024 + j0 + ch8) =
                        *(uint4*)&SMEM[tok * 136 + ch8];
            }
        }
    } else {
        // v epilogue via T[128][72]: rows=channel, cols=pi(token); zero pad-tokens
        int ch0 = j0 - 1024;
#pragma unroll
        for (int h = 0; h < 2; h++) {
            if (h) __syncthreads();
            if (wr == h) {
#pragma unroll
                for (int ii = 0; ii < 4; ii++)
#pragma unroll
                    for (int jj = 0; jj < 4; jj++)
#pragma unroll
                        for (int r = 0; r < 4; r++) {
                            int tok = ii * 16 + quad * 4 + r;       // within 64-half
                            int gi = i0 + h * 64 + tok;
                            u16 val = (gi < NTOK) ? f2bf(acc[ii][jj][r]) : (u16)0;
                            SMEM[(wc * 64 + jj * 16 + l15) * 72 + (tok & 15) * 4 + (tok >> 4)] = val;
                        }
            }
            __syncthreads();
#pragma unroll
            for (int g = 0; g < 4; g++) {
                int unit = g * 256 + t;
                int chl = unit >> 3, tok8 = (unit & 7) * 8;
                int chv = ch0 + chl, hd = chv >> 6, tc = chv & 63;
                *(uint4*)(vT + (((size_t)b * NH + hd) * DH + tc) * NTOKP + i0 + h * 64 + tok8) =
                    *(uint4*)&SMEM[chl * 72 + tok8];
            }
        }
    }
}

// ---------------- attention, no-rescale softmax (bounded scores) ----------------
__global__ __launch_bounds__(256) void k_attn(const u16* __restrict__ qk,
                                              const u16* __restrict__ vT,
                                              const u16* __restrict__ biasC,
                                              u16* __restrict__ attnout) {
    __shared__ u16 Qs[64][72];
    __shared__ u16 Ks[64][72];
    __shared__ u16 Vs[64][72];
    __shared__ u16 Ps[64][72];
    int b = blockIdx.z, m = blockIdx.y, it = blockIdx.x;
    int i0 = it * 64;
    int t = threadIdx.x;
    int w = t >> 6, lane = t & 63, quad = lane >> 4, l15 = lane & 15;
#pragma unroll
    for (int r = 0; r < 2; r++) {       // Q tile (zero OOB rows)
        int row = (t >> 3) + r * 32;
        int t8 = (t & 7) * 8;
        int gi = i0 + row;
        uint4 v;
        if (gi < NTOK) v = *(const uint4*)(qk + ((size_t)b * NTOK + gi) * 1024 + m * DH + t8);
        else v = make_uint4(0, 0, 0, 0);
        *(uint4*)&Qs[row][t8] = v;
    }
    float rs[4] = {0.f, 0.f, 0.f, 0.f};
    f32x4 oacc[4] = {};
    const u16* vbase = vT + ((size_t)b * NH + m) * DH * NTOKP;
    const u16* bC = biasC + (size_t)(m * 10) * 10 * 4096 + (size_t)it * 4096 + t * 16;

    for (int jt = 0; jt < 10; jt++) {
        int j0 = jt * 64;
        __syncthreads();                // prior Ks/Vs reads done
#pragma unroll
        for (int r = 0; r < 2; r++) {   // stage K (rows=j) and V (rows=dh, pi-token cols)
            int row = (t >> 3) + r * 32;
            int c8 = (t & 7) * 8;
            int gj = j0 + row;
            uint4 kv;
            if (gj < NTOK) kv = *(const uint4*)(qk + ((size_t)b * NTOK + gj) * 1024 + 512 + m * DH + c8);
            else kv = make_uint4(0, 0, 0, 0);
            *(uint4*)&Ks[row][c8] = kv;
            uint4 vv = *(const uint4*)(vbase + (size_t)row * NTOKP + j0 + c8);
            *(uint4*)&Vs[row][c8] = vv;
        }
        __syncthreads();
        // S init from C-layout bias (masking pre-folded)
        const u16* bp = bC + (size_t)jt * 10 * 4096;
        uint4 bb0 = *(const uint4*)bp, bb1 = *(const uint4*)(bp + 8);
        u16 bh[16];
        *(uint4*)&bh[0] = bb0; *(uint4*)&bh[8] = bb1;
        f32x4 s[4];
#pragma unroll
        for (int jj = 0; jj < 4; jj++)
#pragma unroll
            for (int r = 0; r < 4; r++) s[jj][r] = bf2f(bh[jj * 4 + r]);
        bf16x8 aq[2];
#pragma unroll
        for (int kk = 0; kk < 2; kk++)
            aq[kk] = *(const bf16x8*)&Qs[w * 16 + l15][kk * 32 + quad * 8];
#pragma unroll
        for (int jj = 0; jj < 4; jj++)
#pragma unroll
            for (int kk = 0; kk < 2; kk++) {
                bf16x8 bk = *(const bf16x8*)&Ks[jj * 16 + l15][kk * 32 + quad * 8];
                s[jj] = __builtin_amdgcn_mfma_f32_16x16x32_bf16(aq[kk], bk, s[jj], 0, 0, 0);
            }
        // P = exp(S) (no max subtraction; constant shift cancels in normalization)
#pragma unroll
        for (int r = 0; r < 4; r++) {
            float p0 = __expf(s[0][r]), p1 = __expf(s[1][r]);
            float p2 = __expf(s[2][r]), p3 = __expf(s[3][r]);
            rs[r] += (p0 + p1) + (p2 + p3);
            uint2 pk;
            pk.x = (unsigned)f2bf_fast(p0) | ((unsigned)f2bf_fast(p1) << 16);
            pk.y = (unsigned)f2bf_fast(p2) | ((unsigned)f2bf_fast(p3) << 16);
            // pi-packed P row: col = l15*4 + jj  (matches vT token order)
            *(uint2*)&Ps[w * 16 + quad * 4 + r][l15 * 4] = pk;
        }
        // same-wave rows only -> no barrier needed before re-read
        bf16x8 ap[2];
#pragma unroll
        for (int kk = 0; kk < 2; kk++)
            ap[kk] = *(const bf16x8*)&Ps[w * 16 + l15][kk * 32 + quad * 8];
#pragma unroll
        for (int tt = 0; tt < 4; tt++)
#pragma unroll
            for (int kk = 0; kk < 2; kk++) {
                bf16x8 bv = *(const bf16x8*)&Vs[tt * 16 + l15][kk * 32 + quad * 8];
                oacc[tt] = __builtin_amdgcn_mfma_f32_16x16x32_bf16(ap[kk], bv, oacc[tt], 0, 0, 0);
            }
    }
    float rinv[4];
#pragma unroll
    for (int r = 0; r < 4; r++) {
        float sum = rs[r];
#pragma unroll
        for (int d = 1; d < 16; d <<= 1) sum += __shfl_xor(sum, d, 64);
        rinv[r] = __frcp_rn(sum);
    }
#pragma unroll
    for (int tt = 0; tt < 4; tt++)
#pragma unroll
        for (int r = 0; r < 4; r++) {
            int gi = i0 + w * 16 + quad * 4 + r;
            if (gi < NTOK)
                attnout[((size_t)b * NTOK + gi) * DDIM + m * DH + tt * 16 + l15] =
                    f2bf(oacc[tt][r] * rinv[r]);
        }
}

// ---------------- out GEMM (C^T): out[b,ch,i] = sum_c attnout[b,i,c]*woT[ch,c] -------
__global__ __launch_bounds__(256) void k_out(const u16* __restrict__ attnout,
                                             const u16* __restrict__ woT,
                                             float* __restrict__ out) {
    __shared__ u16 SMEM[8192];          // As [128][32] | Bs [128][32]
    int b = blockIdx.z, jt = blockIdx.y, it = blockIdx.x;
    int j0 = jt * 128, i0 = it * 128;   // j = channel (M), i = token (N)
    int t = threadIdx.x;
    int w = t >> 6, lane = t & 63, quad = lane >> 4, l15 = lane & 15;
    int wr = w >> 1, wc = w & 1;
    f32x4 acc[4][4] = {};
    const u16* abase = woT + (size_t)j0 * DDIM;
    const u16* bbase = attnout + ((size_t)b * NTOK + i0) * DDIM;
    for (int k0 = 0; k0 < DDIM; k0 += 32) {
        __syncthreads();
#pragma unroll
        for (int c = 0; c < 2; c++) {
            int unit = c * 256 + t;
            int row = unit >> 2, col = (unit & 3) * 8;
            glds16(abase + (size_t)row * DDIM + k0 + col, SMEM + unit * 8);
            glds16(bbase + (size_t)row * DDIM + k0 + col, SMEM + 4096 + unit * 8);
        }
        __syncthreads();
        bf16x8 af[4], bfv[4];
#pragma unroll
        for (int q2 = 0; q2 < 4; q2++) {
            af[q2]  = *(const bf16x8*)&SMEM[(wr * 64 + q2 * 16 + l15) * 32 + quad * 8];
            bfv[q2] = *(const bf16x8*)&SMEM[4096 + (wc * 64 + q2 * 16 + l15) * 32 + quad * 8];
        }
#pragma unroll
        for (int ii = 0; ii < 4; ii++)
#pragma unroll
            for (int jj = 0; jj < 4; jj++)
                acc[ii][jj] = __builtin_amdgcn_mfma_f32_16x16x32_bf16(af[ii], bfv[jj], acc[ii][jj], 0, 0, 0);
    }
    // D rows = channel, cols = token -> coalesced (b, d, n) f32 store
#pragma unroll
    for (int ii = 0; ii < 4; ii++)
#pragma unroll
        for (int jj = 0; jj < 4; jj++) {
            int gi = i0 + wc * 64 + jj * 16 + l15;
            if (gi >= NTOK) continue;
#pragma unroll
            for (int r = 0; r < 4; r++) {
                int gj = j0 + wr * 64 + ii * 16 + quad * 4 + r;
                out[((size_t)b * DDIM + gj) * NTOK + gi] = acc[ii][jj][r];
            }
        }
}

extern "C" void kernel_launch(void* const* d_in, const int* in_sizes, int n_in,
                              void* d_out, int out_size, void* d_ws, size_t ws_size,
                              hipStream_t stream) {
    const float* x    = (const float*)d_in[0];   // (64,512,25,25) f32
    const float* wqkv = (const float*)d_in[1];   // (512,1536) f32
    const float* wout = (const float*)d_in[2];   // (512,512) f32
    const float* rpb  = (const float*)d_in[3];   // (2401,8) f32
    const int*   rpi  = (const int*)d_in[4];     // (625,625) int32
    float* out = (float*)d_out;

    char* ws = (char*)d_ws;
    size_t off = 0;
    auto alloc = [&](size_t nbytes) -> void* {
        void* p = ws + off;
        off += (nbytes + 255) & ~(size_t)255;
        return p;
    };
    u16* tokens   = (u16*)alloc((size_t)NB * NTOK * DDIM * 2);     // 41 MB (reused as attnout)
    u16* qk       = (u16*)alloc((size_t)NB * NTOK * 1024 * 2);     // 82 MB
    u16* vT       = (u16*)alloc((size_t)NB * NH * DH * NTOKP * 2); // 42 MB
    u16* wqkvT    = (u16*)alloc((size_t)1536 * DDIM * 2);
    u16* woutT    = (u16*)alloc((size_t)DDIM * DDIM * 2);
    u16* biasC    = (u16*)alloc((size_t)NH * 100 * 4096 * 2);      // 6.6 MB, C-layout bf16
    u16* attnout  = tokens;  // tokens is dead after k_qkv

    k_transpose_x<<<dim3(10, 8, NB), 256, 0, stream>>>(x, tokens);
    k_transpose_w<<<dim3(1536 / 64, DDIM / 64), 256, 0, stream>>>(wqkv, wqkvT, DDIM, 1536);
    k_transpose_w<<<dim3(DDIM / 64, DDIM / 64), 256, 0, stream>>>(wout, woutT, DDIM, DDIM);
    k_bias<<<dim3(800), 256, 0, stream>>>(rpi, rpb, biasC);
    k_qkv<<<dim3(5, 12, NB), 256, 0, stream>>>(tokens, wqkvT, qk, vT);
    k_attn<<<dim3(10, NH, NB), 256, 0, stream>>>(qk, vT, biasC, attnout);
    k_out<<<dim3(5, 4, NB), 256, 0, stream>>>(attnout, woutT, out);
}